// Round 1
// baseline (3397.197 us; speedup 1.0000x reference)
//
#include <hip/hip_runtime.h>
#include <hip/hip_bf16.h>
#include <stdint.h>

// ---------------------------------------------------------------------------
// NaiveLSTM: B=64, T=1024, I=512, H=512
//   phase 0: convert x->bf16; transpose W,U -> bf16 [2048][512]; init flags/h0
//   phase 1: xW = x @ W   (bf16 MFMA GEMM, 65536x512x2048), bias added later
//   phase 2: sequential LSTM over T=1024 steps.
//            4 groups x 16 batch rows; 16 blocks/group; U^T slice in LDS.
//            h exchanged through an append-only history buffer in ws with
//            LLC-coherent (sc0 sc1) stores/loads + per-block monotonic flags.
// Workspace need: ~389 MiB.
// ---------------------------------------------------------------------------

typedef __attribute__((ext_vector_type(8))) short bf16x8;
typedef __attribute__((ext_vector_type(4))) float f32x4;

constexpr int T_STEPS = 1024;
constexpr int HS = 512;
constexpr int G4 = 2048;
constexpr int NGROUP = 4;   // batch groups, 16 rows each
constexpr int HIST_SLOT_U32 = 16 * 512 / 2;   // 4096 u32 = 16KB per step per group

__device__ __forceinline__ unsigned short f2bf(float f) {
  unsigned u = __float_as_uint(f);
  u += 0x7fffu + ((u >> 16) & 1u);            // RNE
  return (unsigned short)(u >> 16);
}
__device__ __forceinline__ float bf_lo(unsigned u) { return __uint_as_float(u << 16); }
__device__ __forceinline__ float bf_hi(unsigned u) { return __uint_as_float(u & 0xffff0000u); }

__device__ __forceinline__ float fast_sig(float x) {
  return __builtin_amdgcn_rcpf(1.f + __expf(-x));
}
__device__ __forceinline__ float fast_tanh(float x) {
  return 2.f * __builtin_amdgcn_rcpf(1.f + __expf(-2.f * x)) - 1.f;
}

// ----- LLC-coherent (cross-XCD safe) memory ops -----
__device__ __forceinline__ void stg_u32_llc(void* p, unsigned v) {
  asm volatile("global_store_dword %0, %1, off sc0 sc1" :: "v"(p), "v"(v) : "memory");
}
__device__ __forceinline__ unsigned ldg_u32_llc(const void* p) {
  unsigned r;
  asm volatile("global_load_dword %0, %1, off sc0 sc1\n\ts_waitcnt vmcnt(0)"
               : "=v"(r) : "v"(p) : "memory");
  return r;
}
__device__ __forceinline__ void ldg_64B_llc(const void* p, uint4& a, uint4& b, uint4& c, uint4& d) {
  const char* q = (const char*)p;
  asm volatile(
      "global_load_dwordx4 %0, %4, off sc0 sc1\n\t"
      "global_load_dwordx4 %1, %5, off sc0 sc1\n\t"
      "global_load_dwordx4 %2, %6, off sc0 sc1\n\t"
      "global_load_dwordx4 %3, %7, off sc0 sc1\n\t"
      "s_waitcnt vmcnt(0)"
      : "=&v"(a), "=&v"(b), "=&v"(c), "=&v"(d)
      : "v"(q), "v"(q + 16), "v"(q + 32), "v"(q + 48)
      : "memory");
}

// ---------------------------------------------------------------------------
// x fp32 -> bf16 (packed u32 pairs), 8 elems/thread/iter
// ---------------------------------------------------------------------------
__global__ __launch_bounds__(256) void conv_f32_to_bf16(const float* __restrict__ in,
                                                        uint4* __restrict__ out, int n16) {
  int i = blockIdx.x * 256 + threadIdx.x;
  const int stride = gridDim.x * 256;
  for (; i < n16; i += stride) {
    float4 a = ((const float4*)in)[2 * i];
    float4 b = ((const float4*)in)[2 * i + 1];
    uint4 o;
    o.x = (unsigned)f2bf(a.x) | ((unsigned)f2bf(a.y) << 16);
    o.y = (unsigned)f2bf(a.z) | ((unsigned)f2bf(a.w) << 16);
    o.z = (unsigned)f2bf(b.x) | ((unsigned)f2bf(b.y) << 16);
    o.w = (unsigned)f2bf(b.z) | ((unsigned)f2bf(b.w) << 16);
    out[i] = o;
  }
}

// ---------------------------------------------------------------------------
// transpose+convert: in fp32 [R][C] -> out bf16 [C][R]   (for W and U, R=512 C=2048)
// ---------------------------------------------------------------------------
__global__ __launch_bounds__(256) void transpose_to_bf16(const float* __restrict__ in,
                                                         unsigned short* __restrict__ out,
                                                         int R, int C) {
  __shared__ unsigned short tile[64][72];
  const int tx = threadIdx.x & 63, ty = threadIdx.x >> 6;
  const int c0 = blockIdx.x * 64, r0 = blockIdx.y * 64;
#pragma unroll
  for (int rr = ty; rr < 64; rr += 4)
    tile[rr][tx] = f2bf(in[(size_t)(r0 + rr) * C + c0 + tx]);
  __syncthreads();
#pragma unroll
  for (int cc = ty; cc < 64; cc += 4)
    out[(size_t)(c0 + cc) * R + r0 + tx] = tile[tx][cc];
}

// ---------------------------------------------------------------------------
// init: zero flags (64 u32) and h_hist[g][0] (4 x 16KB). Runs every launch so
// graph replays are deterministic.
// ---------------------------------------------------------------------------
__global__ __launch_bounds__(256) void init_ws_kernel(unsigned* __restrict__ flags,
                                                      unsigned* __restrict__ hist) {
  const int i = blockIdx.x * 256 + threadIdx.x;
  if (i < 64) flags[i] = 0;
  if (i < NGROUP * HIST_SLOT_U32) {
    const int g = i >> 12, w = i & 4095;
    hist[(size_t)g * 1025 * HIST_SLOT_U32 + w] = 0;
  }
}

// ---------------------------------------------------------------------------
// Phase 1 GEMM: C[m][n] = sum_k A[m][k] * Bt[n][k]   (bf16 in, bf16 out)
// A = x_bf16 [65536][512], Bt = W^T bf16 [2048][512], C = xW bf16 [65536][2048]
// 128x128 tile, BK=64, 4 waves (2x2 of 64x64), reg-staged LDS.
// ---------------------------------------------------------------------------
__global__ __launch_bounds__(256, 1) void gemm_xw(const unsigned short* __restrict__ A,
                                                  const unsigned short* __restrict__ Bt,
                                                  unsigned short* __restrict__ C) {
  __shared__ __align__(16) char Al[128 * 128];  // [m][128B of k]
  __shared__ __align__(16) char Bl[128 * 128];  // [n][128B of k]
  const int tid = threadIdx.x, lane = tid & 63, wave = tid >> 6;
  const int n0 = blockIdx.x * 128;
  const size_t m0 = (size_t)blockIdx.y * 128;
  const int wm = wave >> 1, wn = wave & 1;
  f32x4 acc[4][4] = {};

  for (int ks = 0; ks < 8; ++ks) {
    const int k0 = ks * 64;
    uint4 va[4], vb[4];
#pragma unroll
    for (int p = 0; p < 4; ++p) {
      const int off = p * 4096 + wave * 1024 + lane * 16;
      const int row = off >> 7, kb = off & 127;
      va[p] = *(const uint4*)(A + (m0 + row) * 512 + k0 + (kb >> 1));
      vb[p] = *(const uint4*)(Bt + (size_t)(n0 + row) * 512 + k0 + (kb >> 1));
    }
    __syncthreads();  // previous iter's fragment reads done
#pragma unroll
    for (int p = 0; p < 4; ++p) {
      const int off = p * 4096 + wave * 1024 + lane * 16;
      *(uint4*)(Al + off) = va[p];
      *(uint4*)(Bl + off) = vb[p];
    }
    __syncthreads();
#pragma unroll
    for (int kk = 0; kk < 2; ++kk) {
      const int kb = (kk * 32 + (lane >> 4) * 8) * 2;
      bf16x8 av[4], bv[4];
#pragma unroll
      for (int i = 0; i < 4; ++i)
        av[i] = *(const bf16x8*)(Al + (wm * 64 + i * 16 + (lane & 15)) * 128 + kb);
#pragma unroll
      for (int j = 0; j < 4; ++j)
        bv[j] = *(const bf16x8*)(Bl + (wn * 64 + j * 16 + (lane & 15)) * 128 + kb);
#pragma unroll
      for (int i = 0; i < 4; ++i)
#pragma unroll
        for (int j = 0; j < 4; ++j)
          acc[i][j] = __builtin_amdgcn_mfma_f32_16x16x32_bf16(av[i], bv[j], acc[i][j], 0, 0, 0);
    }
    __syncthreads();
  }
  // epilogue: D col = lane&15, row = (lane>>4)*4 + r  (m89-verified layout)
#pragma unroll
  for (int i = 0; i < 4; ++i)
#pragma unroll
    for (int j = 0; j < 4; ++j) {
      const int col = n0 + wn * 64 + j * 16 + (lane & 15);
#pragma unroll
      for (int r = 0; r < 4; ++r) {
        const int row = wm * 64 + i * 16 + (lane >> 4) * 4 + r;
        C[(m0 + row) * (size_t)2048 + col] = f2bf(acc[i][j][r]);
      }
    }
}

// ---------------------------------------------------------------------------
// Phase 2: sequential LSTM.
// grid = 64 blocks x 256 threads. group g = blockIdx&3 (16 batch rows),
// block-in-group bg = blockIdx>>2 owns h-cols [bg*32, bg*32+32) i.e. U^T rows
// {gate*512 + bg*32 + nc}. U slice (512x128 bf16 = 128KB) lives in LDS.
// wave w computes gate w's 16x32 tile; gates routed via LDS for elementwise.
// ---------------------------------------------------------------------------
__global__ __launch_bounds__(256, 1) void lstm_seq(const unsigned* __restrict__ xW,       // bf16 pairs [65536][1024]
                                                   const unsigned short* __restrict__ Ut, // bf16 [2048][512]
                                                   const float* __restrict__ bias,        // [2048]
                                                   float* __restrict__ out,
                                                   unsigned* __restrict__ hist,           // bf16 pairs
                                                   unsigned* __restrict__ flags) {
  __shared__ __align__(16) unsigned short Ul[128 * 512];  // [lc][k] swizzled, 128KB
  __shared__ __align__(16) unsigned short hl[16 * 512];   // [m][k]  swizzled, 16KB
  __shared__ float gl[4][16][32];                          // gate tiles, 8KB
  __shared__ float cl[16][32];                             // cell state, 2KB

  const int tid = threadIdx.x, lane = tid & 63, wave = tid >> 6;
  const int g = blockIdx.x & 3;
  const int bg = blockIdx.x >> 2;
  const int c0 = bg * 32;
  const int bm0 = g * 16;

  // ---- one-time: stage U^T slice into LDS (swizzled [lc][k]) ----
  for (int lc = wave; lc < 128; lc += 4) {
    const int gate = lc >> 5, nc = lc & 31;
    const int gcol = gate * 512 + c0 + nc;
    uint4 v = *(const uint4*)(Ut + (size_t)gcol * 512 + lane * 8);
    const int off = (lc * 1024 + lane * 16) ^ ((lc & 7) << 4);
    *(uint4*)((char*)Ul + off) = v;
  }
  if (tid < 128) ((float4*)cl)[tid] = make_float4(0.f, 0.f, 0.f, 0.f);

  const int m = tid >> 4;          // batch row within group
  const int np = (tid & 15) * 2;   // col pair within block's 32 cols
  float bs[4][2];
#pragma unroll
  for (int gg = 0; gg < 4; ++gg) {
    bs[gg][0] = bias[gg * 512 + c0 + np];
    bs[gg][1] = bias[gg * 512 + c0 + np + 1];
  }
  __syncthreads();

  const int am = lane & 15;
  const int asw = (am & 7) << 4;
  const int lc0 = wave * 32 + (lane & 15);
  const int lc1 = lc0 + 16;
  const int bsw0 = (lc0 & 7) << 4;
  const int bsw1 = (lc1 & 7) << 4;
  const int kgb = (lane >> 4) * 16;  // byte offset of this lane's k-chunk

  for (int t = 0; t < T_STEPS; ++t) {
    // prefetch this step's xW slice (independent of h) to hide HBM latency
    unsigned xwv[4];
    {
      const unsigned* base = xW + ((size_t)(bm0 + m) * T_STEPS + t) * (G4 / 2);
#pragma unroll
      for (int gg = 0; gg < 4; ++gg) xwv[gg] = base[(gg * 512 + c0 + np) >> 1];
    }
    // wait for all 16 producer blocks of this group to have published h_t
    if (wave == 0) {
      const unsigned tgt = (unsigned)t;
      for (;;) {
        unsigned v = ldg_u32_llc(&flags[g * 16 + (lane & 15)]);
        if (__all((int)(v >= tgt))) break;
      }
    }
    __syncthreads();
    // load full h_t (16x512 bf16 = 16KB) from history, stage to LDS swizzled
    {
      const char* hb = (const char*)hist + (size_t)(g * 1025 + t) * 16384;
      uint4 a, b, c, d;
      ldg_64B_llc(hb + tid * 64, a, b, c, d);
      char* dst = (char*)hl;
      const int rowb = (tid >> 4) * 1024;
      const int colb = (tid & 15) * 64;
      const int sw = ((tid >> 4) & 7) << 4;
      *(uint4*)(dst + ((rowb + colb) ^ sw)) = a;
      *(uint4*)(dst + ((rowb + colb + 16) ^ sw)) = b;
      *(uint4*)(dst + ((rowb + colb + 32) ^ sw)) = c;
      *(uint4*)(dst + ((rowb + colb + 48) ^ sw)) = d;
    }
    __syncthreads();

    // h_t @ U slice: wave = gate, two 16x16 n-tiles, K=512
    f32x4 acc0 = {0.f, 0.f, 0.f, 0.f}, acc1 = {0.f, 0.f, 0.f, 0.f};
#pragma unroll
    for (int ks = 0; ks < 16; ++ks) {
      const int kb = ks * 64 + kgb;
      bf16x8 av = *(const bf16x8*)((const char*)hl + ((am * 1024 + kb) ^ asw));
      bf16x8 b0 = *(const bf16x8*)((const char*)Ul + ((lc0 * 1024 + kb) ^ bsw0));
      bf16x8 b1 = *(const bf16x8*)((const char*)Ul + ((lc1 * 1024 + kb) ^ bsw1));
      acc0 = __builtin_amdgcn_mfma_f32_16x16x32_bf16(av, b0, acc0, 0, 0, 0);
      acc1 = __builtin_amdgcn_mfma_f32_16x16x32_bf16(av, b1, acc1, 0, 0, 0);
    }
    // route gate tiles through LDS (waves hold different gates)
    {
      const int col = lane & 15, row4 = (lane >> 4) * 4;
#pragma unroll
      for (int r = 0; r < 4; ++r) {
        gl[wave][row4 + r][col] = acc0[r];
        gl[wave][row4 + r][col + 16] = acc1[r];
      }
    }
    __syncthreads();

    // elementwise LSTM cell for this thread's (m, np..np+1)
    {
      float h0, h1, cA, cB;
      {
        const int nc = np;
        const float xi = gl[0][m][nc] + bf_lo(xwv[0]) + bs[0][0];
        const float xf = gl[1][m][nc] + bf_lo(xwv[1]) + bs[1][0];
        const float xg = gl[2][m][nc] + bf_lo(xwv[2]) + bs[2][0];
        const float xo = gl[3][m][nc] + bf_lo(xwv[3]) + bs[3][0];
        const float it = fast_sig(xi), ft = fast_sig(xf);
        const float gt = fast_tanh(xg), ot = fast_sig(xo);
        cA = ft * cl[m][nc] + it * gt;
        h0 = ot * fast_tanh(cA);
        cl[m][nc] = cA;
      }
      {
        const int nc = np + 1;
        const float xi = gl[0][m][nc] + bf_hi(xwv[0]) + bs[0][1];
        const float xf = gl[1][m][nc] + bf_hi(xwv[1]) + bs[1][1];
        const float xg = gl[2][m][nc] + bf_hi(xwv[2]) + bs[2][1];
        const float xo = gl[3][m][nc] + bf_hi(xwv[3]) + bs[3][1];
        const float it = fast_sig(xi), ft = fast_sig(xf);
        const float gt = fast_tanh(xg), ot = fast_sig(xo);
        cB = ft * cl[m][nc] + it * gt;
        h1 = ot * fast_tanh(cB);
        cl[m][nc] = cB;
      }
      // hidden_seq output (fp32)
      *(float2*)(out + ((size_t)(bm0 + m) * T_STEPS + t) * HS + c0 + np) = make_float2(h0, h1);
      // publish h_{t+1} slice (bf16, LLC-coherent)
      const unsigned hp = (unsigned)f2bf(h0) | ((unsigned)f2bf(h1) << 16);
      stg_u32_llc(hist + (size_t)(g * 1025 + t + 1) * HIST_SLOT_U32 + m * 256 + ((c0 + np) >> 1), hp);
      if (t == T_STEPS - 1) {
        const size_t hs_total = (size_t)64 * T_STEPS * HS;
        *(float2*)(out + hs_total + (size_t)(bm0 + m) * HS + c0 + np) = make_float2(h0, h1);
        *(float2*)(out + hs_total + 64 * HS + (size_t)(bm0 + m) * HS + c0 + np) = make_float2(cA, cB);
      }
    }
    __syncthreads();  // drains all waves' vmem stores before flag bump
    if (tid == 0) stg_u32_llc(&flags[g * 16 + bg], (unsigned)(t + 1));
  }
}

// ---------------------------------------------------------------------------
extern "C" void kernel_launch(void* const* d_in, const int* in_sizes, int n_in,
                              void* d_out, int out_size, void* d_ws, size_t ws_size,
                              hipStream_t stream) {
  const float* x = (const float*)d_in[0];
  const float* W = (const float*)d_in[1];
  const float* U = (const float*)d_in[2];
  const float* bias = (const float*)d_in[3];
  float* out = (float*)d_out;
  char* ws = (char*)d_ws;

  size_t off = 0;
  unsigned* flags = (unsigned*)(ws + off);        off += 4096;
  unsigned short* x_bf = (unsigned short*)(ws + off); off += (size_t)65536 * 512 * 2;   // 64MB
  unsigned short* Wt = (unsigned short*)(ws + off);   off += (size_t)2048 * 512 * 2;    // 2MB
  unsigned short* Ut = (unsigned short*)(ws + off);   off += (size_t)2048 * 512 * 2;    // 2MB
  unsigned* hist = (unsigned*)(ws + off);             off += (size_t)NGROUP * 1025 * 16384; // 64MB
  unsigned short* xWb = (unsigned short*)(ws + off);  off += (size_t)65536 * 2048 * 2;  // 256MB
  if (ws_size < off) return;  // workspace too small -> fail visibly

  conv_f32_to_bf16<<<4096, 256, 0, stream>>>(x, (uint4*)x_bf, 33554432 / 8);
  transpose_to_bf16<<<dim3(32, 8), 256, 0, stream>>>(W, Wt, 512, 2048);
  transpose_to_bf16<<<dim3(32, 8), 256, 0, stream>>>(U, Ut, 512, 2048);
  init_ws_kernel<<<64, 256, 0, stream>>>(flags, hist);
  gemm_xw<<<dim3(16, 512), 256, 0, stream>>>(x_bf, Wt, xWb);
  lstm_seq<<<64, 256, 0, stream>>>((const unsigned*)xWb, Ut, bias, out, hist, flags);
}

// Round 2
// 2784.349 us; speedup vs baseline: 1.2201x; 1.2201x over previous
//
#include <hip/hip_runtime.h>
#include <hip/hip_bf16.h>
#include <stdint.h>

// ---------------------------------------------------------------------------
// NaiveLSTM: B=64, T=1024, I=512, H=512
//   phase 0: convert x->bf16; transpose W,U -> bf16 [2048][512]; init hist
//            (slot 0 = h0 = 0, slots 1..1024 = bf16-NaN sentinel)
//   phase 1: xW = x @ W  (bf16 MFMA GEMM, global_load_lds staging)
//   phase 2: sequential LSTM, 4 groups x 16 blocks. U fragments in REGISTERS
//            (wave = gate). h exchanged via sentinel-initialized history
//            buffer: consumers poll the DATA itself with sc0 sc1 loads ->
//            single LLC round trip per step. hist store issued before fp32
//            out store so the HBM store is off the inter-block critical path.
// ---------------------------------------------------------------------------

typedef __attribute__((ext_vector_type(8))) short bf16x8;
typedef __attribute__((ext_vector_type(4))) float f32x4;

constexpr int T_STEPS = 1024;
constexpr int HS = 512;
constexpr int G4 = 2048;
constexpr int NGROUP = 4;
constexpr unsigned SENT = 0x7FC07FC0u;          // bf16 NaN pair — h can never be NaN
constexpr int HIST_SLOT_U32 = 16 * 512 / 2;     // 4096 u32 = 16KB per step per group

__device__ __forceinline__ unsigned short f2bf(float f) {
  unsigned u = __float_as_uint(f);
  u += 0x7fffu + ((u >> 16) & 1u);              // RNE
  return (unsigned short)(u >> 16);
}
__device__ __forceinline__ float bf_lo(unsigned u) { return __uint_as_float(u << 16); }
__device__ __forceinline__ float bf_hi(unsigned u) { return __uint_as_float(u & 0xffff0000u); }

__device__ __forceinline__ float fast_sig(float x) {
  return __builtin_amdgcn_rcpf(1.f + __expf(-x));
}
__device__ __forceinline__ float fast_tanh(float x) {
  return 2.f * __builtin_amdgcn_rcpf(1.f + __expf(-2.f * x)) - 1.f;
}

// ----- LLC-coherent (cross-XCD safe) memory ops -----
__device__ __forceinline__ void stg_u32_llc(void* p, unsigned v) {
  asm volatile("global_store_dword %0, %1, off sc0 sc1" :: "v"(p), "v"(v) : "memory");
}
__device__ __forceinline__ void ldg_64B_llc(const void* p, uint4& a, uint4& b, uint4& c, uint4& d) {
  const char* q = (const char*)p;
  asm volatile(
      "global_load_dwordx4 %0, %4, off sc0 sc1\n\t"
      "global_load_dwordx4 %1, %5, off sc0 sc1\n\t"
      "global_load_dwordx4 %2, %6, off sc0 sc1\n\t"
      "global_load_dwordx4 %3, %7, off sc0 sc1\n\t"
      "s_waitcnt vmcnt(0)"
      : "=&v"(a), "=&v"(b), "=&v"(c), "=&v"(d)
      : "v"(q), "v"(q + 16), "v"(q + 32), "v"(q + 48)
      : "memory");
}

// ---------------------------------------------------------------------------
__global__ __launch_bounds__(256) void conv_f32_to_bf16(const float* __restrict__ in,
                                                        uint4* __restrict__ out, int n16) {
  int i = blockIdx.x * 256 + threadIdx.x;
  const int stride = gridDim.x * 256;
  for (; i < n16; i += stride) {
    float4 a = ((const float4*)in)[2 * i];
    float4 b = ((const float4*)in)[2 * i + 1];
    uint4 o;
    o.x = (unsigned)f2bf(a.x) | ((unsigned)f2bf(a.y) << 16);
    o.y = (unsigned)f2bf(a.z) | ((unsigned)f2bf(a.w) << 16);
    o.z = (unsigned)f2bf(b.x) | ((unsigned)f2bf(b.y) << 16);
    o.w = (unsigned)f2bf(b.z) | ((unsigned)f2bf(b.w) << 16);
    out[i] = o;
  }
}

// ---------------------------------------------------------------------------
__global__ __launch_bounds__(256) void transpose_to_bf16(const float* __restrict__ in,
                                                         unsigned short* __restrict__ out,
                                                         int R, int C) {
  __shared__ unsigned short tile[64][72];
  const int tx = threadIdx.x & 63, ty = threadIdx.x >> 6;
  const int c0 = blockIdx.x * 64, r0 = blockIdx.y * 64;
#pragma unroll
  for (int rr = ty; rr < 64; rr += 4)
    tile[rr][tx] = f2bf(in[(size_t)(r0 + rr) * C + c0 + tx]);
  __syncthreads();
#pragma unroll
  for (int cc = ty; cc < 64; cc += 4)
    out[(size_t)(c0 + cc) * R + r0 + tx] = tile[tx][cc];
}

// ---------------------------------------------------------------------------
// hist init: per group, slot 0 (h0) = 0.0, slots 1..1024 = sentinel.
// Must run EVERY launch (graph replays reuse the buffer).
// ---------------------------------------------------------------------------
__global__ __launch_bounds__(256) void init_hist(uint4* __restrict__ hist4) {
  const unsigned per_g = 1025u * 1024u;          // uint4 per group region
  const unsigned total = NGROUP * per_g;         // 4,198,400
  unsigned i = blockIdx.x * 256 + threadIdx.x;
  const unsigned stride = gridDim.x * 256;
  for (; i < total; i += stride) {
    const unsigned w = i % per_g;
    const unsigned v = (w < 1024u) ? 0u : SENT;  // slot 0 = 1024 uint4
    hist4[i] = make_uint4(v, v, v, v);
  }
}

// ---------------------------------------------------------------------------
// Phase 1 GEMM: C[m][n] = sum_k A[m][k] * Bt[n][k]  (bf16 in/out)
// 128x128 tile, BK=64, 4 waves (2x2 of 64x64), global_load_lds dwordx4
// staging (m97 pattern: wave-uniform LDS base + lane*16, per-lane global src)
// ---------------------------------------------------------------------------
__global__ __launch_bounds__(256, 1) void gemm_xw(const unsigned short* __restrict__ A,
                                                  const unsigned short* __restrict__ Bt,
                                                  unsigned short* __restrict__ C) {
  __shared__ __align__(16) char Al[128 * 128];  // [m][128B of k]
  __shared__ __align__(16) char Bl[128 * 128];  // [n][128B of k]
  const int tid = threadIdx.x, lane = tid & 63, wave = tid >> 6;
  const int n0 = blockIdx.x * 128;
  const size_t m0 = (size_t)blockIdx.y * 128;
  const int wm = wave >> 1, wn = wave & 1;
  f32x4 acc[4][4] = {};

  for (int ks = 0; ks < 8; ++ks) {
    const int k0 = ks * 64;
    if (ks) __syncthreads();  // prior iter's ds_reads done before overwrite
#pragma unroll
    for (int p = 0; p < 4; ++p) {
      const int off = p * 4096 + wave * 1024 + lane * 16;
      const int row = off >> 7, kb = off & 127;
      const unsigned short* ga = A + (m0 + row) * 512 + k0 + (kb >> 1);
      const unsigned short* gb = Bt + (size_t)(n0 + row) * 512 + k0 + (kb >> 1);
      __builtin_amdgcn_global_load_lds(
          (const __attribute__((address_space(1))) void*)ga,
          (__attribute__((address_space(3))) void*)(Al + p * 4096 + wave * 1024), 16, 0, 0);
      __builtin_amdgcn_global_load_lds(
          (const __attribute__((address_space(1))) void*)gb,
          (__attribute__((address_space(3))) void*)(Bl + p * 4096 + wave * 1024), 16, 0, 0);
    }
    __syncthreads();  // implicit vmcnt(0) drain -> LDS valid
#pragma unroll
    for (int kk = 0; kk < 2; ++kk) {
      const int kb = (kk * 32 + (lane >> 4) * 8) * 2;
      bf16x8 av[4], bv[4];
#pragma unroll
      for (int i = 0; i < 4; ++i)
        av[i] = *(const bf16x8*)(Al + (wm * 64 + i * 16 + (lane & 15)) * 128 + kb);
#pragma unroll
      for (int j = 0; j < 4; ++j)
        bv[j] = *(const bf16x8*)(Bl + (wn * 64 + j * 16 + (lane & 15)) * 128 + kb);
#pragma unroll
      for (int i = 0; i < 4; ++i)
#pragma unroll
        for (int j = 0; j < 4; ++j)
          acc[i][j] = __builtin_amdgcn_mfma_f32_16x16x32_bf16(av[i], bv[j], acc[i][j], 0, 0, 0);
    }
  }
  // epilogue: D col = lane&15, row = (lane>>4)*4 + r
#pragma unroll
  for (int i = 0; i < 4; ++i)
#pragma unroll
    for (int j = 0; j < 4; ++j) {
      const int col = n0 + wn * 64 + j * 16 + (lane & 15);
#pragma unroll
      for (int r = 0; r < 4; ++r) {
        const int row = wm * 64 + i * 16 + (lane >> 4) * 4 + r;
        C[(m0 + row) * (size_t)2048 + col] = f2bf(acc[i][j][r]);
      }
    }
}

// ---------------------------------------------------------------------------
// Phase 2: sequential LSTM.
// grid = 64 blocks x 256 threads. group g = blockIdx&3 (16 batch rows),
// bg = blockIdx>>2 owns h-cols [bg*32, bg*32+32). U fragments live in
// REGISTERS (wave = gate, 32 x bf16x8 = 128 VGPR/lane). Per step:
//   poll h_t data (sentinel) -> stage to LDS (dbuf) -> sync A ->
//   16x MFMA pairs -> gl route -> sync B -> elementwise ->
//   hist store (sc0 sc1, FIRST) -> fp32 out store (lazy).
// ---------------------------------------------------------------------------
__global__ __launch_bounds__(256, 1) void lstm_seq(const unsigned* __restrict__ xW,       // bf16 pairs [65536][1024]
                                                   const unsigned short* __restrict__ Ut, // bf16 [2048][512]
                                                   const float* __restrict__ bias,        // [2048]
                                                   float* __restrict__ out,
                                                   unsigned* __restrict__ hist) {
  __shared__ __align__(16) unsigned short hl[2][16 * 512];  // double-buffered, 32KB
  __shared__ float gl[4][16][32];                            // gate tiles, 8KB
  __shared__ float cl[16][32];                               // cell state, 2KB

  const int tid = threadIdx.x, lane = tid & 63, wave = tid >> 6;
  const int g = blockIdx.x & 3;
  const int bg = blockIdx.x >> 2;
  const int c0 = bg * 32;
  const int bm0 = g * 16;

  // ---- one-time: U^T fragments into registers (wave = gate) ----
  bf16x8 uf[16][2];
#pragma unroll
  for (int ks = 0; ks < 16; ++ks)
#pragma unroll
    for (int j = 0; j < 2; ++j)
      uf[ks][j] = *(const bf16x8*)(Ut +
          (size_t)(wave * 512 + c0 + j * 16 + (lane & 15)) * 512 + ks * 32 + (lane >> 4) * 8);

  if (tid < 128) ((float4*)cl)[tid] = make_float4(0.f, 0.f, 0.f, 0.f);

  const int m = tid >> 4;          // batch row within group
  const int np = (tid & 15) * 2;   // col pair within block's 32 cols
  float bs[4][2];
#pragma unroll
  for (int gg = 0; gg < 4; ++gg) {
    bs[gg][0] = bias[gg * 512 + c0 + np];
    bs[gg][1] = bias[gg * 512 + c0 + np + 1];
  }

  const int am = lane & 15;
  const int asw = (am & 7) << 4;
  const int kgb = (lane >> 4) * 16;           // byte offset of lane's k-chunk
  const int rowb = (tid >> 4) * 1024;         // h-staging LDS offsets
  const int colb = (tid & 15) * 64;
  const int sw = ((tid >> 4) & 7) << 4;

  __syncthreads();  // cl init visible

  for (int t = 0; t < T_STEPS; ++t) {
    // xW slice loads (independent of h): issued first, complete under the poll
    unsigned xwv[4];
    {
      const unsigned* base = xW + ((size_t)(bm0 + m) * T_STEPS + t) * (G4 / 2);
#pragma unroll
      for (int gg = 0; gg < 4; ++gg) xwv[gg] = base[(gg * 512 + c0 + np) >> 1];
    }
    // poll h_t DATA directly (single LLC round trip; loaded regs are the data)
    uint4 a, b, c, d;
    {
      const char* hb = (const char*)hist + (size_t)(g * 1025 + t) * 16384 + tid * 64;
      for (;;) {
        ldg_64B_llc(hb, a, b, c, d);
        const bool bad = (a.x == SENT) | (a.y == SENT) | (a.z == SENT) | (a.w == SENT) |
                         (b.x == SENT) | (b.y == SENT) | (b.z == SENT) | (b.w == SENT) |
                         (c.x == SENT) | (c.y == SENT) | (c.z == SENT) | (c.w == SENT) |
                         (d.x == SENT) | (d.y == SENT) | (d.z == SENT) | (d.w == SENT);
        if (!bad) break;
      }
    }
    // stage h_t to LDS (swizzled)
    {
      char* dst = (char*)hl[t & 1];
      *(uint4*)(dst + ((rowb + colb) ^ sw)) = a;
      *(uint4*)(dst + ((rowb + colb + 16) ^ sw)) = b;
      *(uint4*)(dst + ((rowb + colb + 32) ^ sw)) = c;
      *(uint4*)(dst + ((rowb + colb + 48) ^ sw)) = d;
    }
    __syncthreads();  // sync A

    // h_t @ U slice: wave = gate, two 16x16 n-tiles, K=512, B from registers
    f32x4 acc0 = {0.f, 0.f, 0.f, 0.f}, acc1 = {0.f, 0.f, 0.f, 0.f};
    const char* hbase = (const char*)hl[t & 1];
#pragma unroll
    for (int ks = 0; ks < 16; ++ks) {
      bf16x8 av = *(const bf16x8*)(hbase + ((am * 1024 + ks * 64 + kgb) ^ asw));
      acc0 = __builtin_amdgcn_mfma_f32_16x16x32_bf16(av, uf[ks][0], acc0, 0, 0, 0);
      acc1 = __builtin_amdgcn_mfma_f32_16x16x32_bf16(av, uf[ks][1], acc1, 0, 0, 0);
    }
    // route gate tiles through LDS
    {
      const int col = lane & 15, row4 = (lane >> 4) * 4;
#pragma unroll
      for (int r = 0; r < 4; ++r) {
        gl[wave][row4 + r][col] = acc0[r];
        gl[wave][row4 + r][col + 16] = acc1[r];
      }
    }
    __syncthreads();  // sync B

    // elementwise LSTM cell for this thread's (m, np..np+1)
    {
      float h0, h1, cA, cB;
      {
        const int nc = np;
        const float xi = gl[0][m][nc] + bf_lo(xwv[0]) + bs[0][0];
        const float xf = gl[1][m][nc] + bf_lo(xwv[1]) + bs[1][0];
        const float xg = gl[2][m][nc] + bf_lo(xwv[2]) + bs[2][0];
        const float xo = gl[3][m][nc] + bf_lo(xwv[3]) + bs[3][0];
        const float it = fast_sig(xi), ft = fast_sig(xf);
        const float gt = fast_tanh(xg), ot = fast_sig(xo);
        cA = ft * cl[m][nc] + it * gt;
        h0 = ot * fast_tanh(cA);
        cl[m][nc] = cA;
      }
      {
        const int nc = np + 1;
        const float xi = gl[0][m][nc] + bf_hi(xwv[0]) + bs[0][1];
        const float xf = gl[1][m][nc] + bf_hi(xwv[1]) + bs[1][1];
        const float xg = gl[2][m][nc] + bf_hi(xwv[2]) + bs[2][1];
        const float xo = gl[3][m][nc] + bf_hi(xwv[3]) + bs[3][1];
        const float it = fast_sig(xi), ft = fast_sig(xf);
        const float gt = fast_tanh(xg), ot = fast_sig(xo);
        cB = ft * cl[m][nc] + it * gt;
        h1 = ot * fast_tanh(cB);
        cl[m][nc] = cB;
      }
      // publish h_{t+1} slice FIRST (this is the inter-block critical path)
      const unsigned hp = (unsigned)f2bf(h0) | ((unsigned)f2bf(h1) << 16);
      stg_u32_llc(hist + (size_t)(g * 1025 + t + 1) * HIST_SLOT_U32 + m * 256 + ((c0 + np) >> 1), hp);
      // fp32 hidden_seq output (retires lazily under next step's poll)
      *(float2*)(out + ((size_t)(bm0 + m) * T_STEPS + t) * HS + c0 + np) = make_float2(h0, h1);
      if (t == T_STEPS - 1) {
        const size_t hs_total = (size_t)64 * T_STEPS * HS;
        *(float2*)(out + hs_total + (size_t)(bm0 + m) * HS + c0 + np) = make_float2(h0, h1);
        *(float2*)(out + hs_total + 64 * HS + (size_t)(bm0 + m) * HS + c0 + np) = make_float2(cA, cB);
      }
    }
    // no end barrier: hl is double-buffered; gl rewrite is fenced by sync A
  }
}

// ---------------------------------------------------------------------------
extern "C" void kernel_launch(void* const* d_in, const int* in_sizes, int n_in,
                              void* d_out, int out_size, void* d_ws, size_t ws_size,
                              hipStream_t stream) {
  const float* x = (const float*)d_in[0];
  const float* W = (const float*)d_in[1];
  const float* U = (const float*)d_in[2];
  const float* bias = (const float*)d_in[3];
  float* out = (float*)d_out;
  char* ws = (char*)d_ws;

  size_t off = 0;
  unsigned short* x_bf = (unsigned short*)(ws + off); off += (size_t)65536 * 512 * 2;       // 64MB
  unsigned short* Wt = (unsigned short*)(ws + off);   off += (size_t)2048 * 512 * 2;        // 2MB
  unsigned short* Ut = (unsigned short*)(ws + off);   off += (size_t)2048 * 512 * 2;        // 2MB
  unsigned* hist = (unsigned*)(ws + off);             off += (size_t)NGROUP * 1025 * 16384; // 67MB
  unsigned short* xWb = (unsigned short*)(ws + off);  off += (size_t)65536 * 2048 * 2;      // 256MB
  if (ws_size < off) return;  // workspace too small -> fail visibly

  conv_f32_to_bf16<<<4096, 256, 0, stream>>>(x, (uint4*)x_bf, 33554432 / 8);
  transpose_to_bf16<<<dim3(32, 8), 256, 0, stream>>>(W, Wt, 512, 2048);
  transpose_to_bf16<<<dim3(32, 8), 256, 0, stream>>>(U, Ut, 512, 2048);
  init_hist<<<2048, 256, 0, stream>>>((uint4*)hist);
  gemm_xw<<<dim3(16, 512), 256, 0, stream>>>(x_bf, Wt, xWb);
  lstm_seq<<<64, 256, 0, stream>>>((const unsigned*)xWb, Ut, bias, out, hist);
}